// Round 7
// baseline (427.766 us; speedup 1.0000x reference)
//
#include <hip/hip_runtime.h>
#include <math.h>
#include <stdint.h>

#define B_    4
#define NQ_   100
#define HW_   4096
#define D_    1024
#define H_    16
#define HD_   64
#define NCH_  8          // key chunks per (b,h) for split-K flash
#define KCH_  (HW_/NCH_) // 512 keys per chunk
#define QT_   32         // queries per tile (4 tiles cover 100, padded)
#define MP_   512        // padded M for small GEMMs (400 -> 512)

typedef __attribute__((ext_vector_type(8))) short short8;
typedef __attribute__((ext_vector_type(8))) unsigned short ushort8v;
typedef __attribute__((ext_vector_type(4))) float f32x4;

// fp32 -> bf16 RNE
__device__ __forceinline__ unsigned short f2bf(float f) {
    unsigned int u = __float_as_uint(f);
    u += 0x7fffu + ((u >> 16) & 1u);
    return (unsigned short)(u >> 16);
}
__device__ __forceinline__ float bf2f(unsigned short h) {
    return __uint_as_float(((unsigned int)h) << 16);
}

// async global->LDS 16B
__device__ __forceinline__ void gl2lds16(const void* g, void* l) {
    typedef __attribute__((address_space(1))) unsigned int gu32;
    typedef __attribute__((address_space(3))) unsigned int lu32;
    __builtin_amdgcn_global_load_lds(
        reinterpret_cast<gu32*>(reinterpret_cast<uintptr_t>(g)),
        reinterpret_cast<lu32*>(reinterpret_cast<uintptr_t>(l)),
        16, 0, 0);
}

// ---------------------------------------------------------------------------
// LayerNorm + bf16: wave-per-row (no block barriers). 4 rows per 256-block.
// Rows >= real_rows write zeros (padding).
// ---------------------------------------------------------------------------
__global__ __launch_bounds__(256) void ln_bf16_kernel(
    const float* __restrict__ x, const float* __restrict__ g,
    const float* __restrict__ be, unsigned short* __restrict__ y, int real_rows)
{
    const int wv = threadIdx.x >> 6, lane = threadIdx.x & 63;
    const int row = blockIdx.x * 4 + wv;
    unsigned short* yr = y + (size_t)row * D_;
    if (row >= real_rows) {
        #pragma unroll
        for (int k = 0; k < 4; ++k)
            *reinterpret_cast<ushort4*>(yr + lane*4 + k*256) = make_ushort4(0,0,0,0);
        return;
    }
    const float* xr = x + (size_t)row * D_;
    float4 v[4];
    float s = 0.f, ss = 0.f;
    #pragma unroll
    for (int k = 0; k < 4; ++k) {
        v[k] = *reinterpret_cast<const float4*>(xr + lane*4 + k*256);
        s  += v[k].x + v[k].y + v[k].z + v[k].w;
        ss += v[k].x*v[k].x + v[k].y*v[k].y + v[k].z*v[k].z + v[k].w*v[k].w;
    }
    #pragma unroll
    for (int o = 1; o < 64; o <<= 1) {
        s  += __shfl_xor(s,  o);
        ss += __shfl_xor(ss, o);
    }
    const float mu = s * (1.0f / D_);
    const float rs = rsqrtf(ss * (1.0f / D_) - mu*mu + 1e-5f);
    #pragma unroll
    for (int k = 0; k < 4; ++k) {
        const float4 gg = *reinterpret_cast<const float4*>(g  + lane*4 + k*256);
        const float4 bb = *reinterpret_cast<const float4*>(be + lane*4 + k*256);
        ushort4 o;
        o.x = f2bf((v[k].x - mu) * rs * gg.x + bb.x);
        o.y = f2bf((v[k].y - mu) * rs * gg.y + bb.y);
        o.z = f2bf((v[k].z - mu) * rs * gg.z + bb.z);
        o.w = f2bf((v[k].w - mu) * rs * gg.w + bb.w);
        *reinterpret_cast<ushort4*>(yr + lane*4 + k*256) = o;
    }
}

// ---------------------------------------------------------------------------
// fp32 -> bf16 convert (flat float4 per thread)
// ---------------------------------------------------------------------------
__global__ __launch_bounds__(256) void wconv_kernel(
    const float* __restrict__ w, unsigned short* __restrict__ wb)
{
    const int i = blockIdx.x * 256 + threadIdx.x;
    const float4 v = reinterpret_cast<const float4*>(w)[i];
    ushort4 o;
    o.x = f2bf(v.x); o.y = f2bf(v.y); o.z = f2bf(v.z); o.w = f2bf(v.w);
    reinterpret_cast<ushort4*>(wb)[i] = o;
}

// ---------------------------------------------------------------------------
// ctxacc/L -> ctx, then [hi | lo | hi] bf16, row stride 3072. Pad rows zeroed.
// ---------------------------------------------------------------------------
__global__ __launch_bounds__(256) void hilo_a_kernel(
    const float* __restrict__ ctxacc, const float* __restrict__ Lacc,
    unsigned short* __restrict__ y)
{
    const int row = blockIdx.x;   // 0..511 (tight out-GEMM rows; >=400 pad)
    const int tid = threadIdx.x;
    unsigned short* yr = y + (size_t)row * 3072;
    if (row >= B_*NQ_) {
        const ushort4 z = make_ushort4(0,0,0,0);
        reinterpret_cast<ushort4*>(yr)[tid]        = z;
        reinterpret_cast<ushort4*>(yr + 1024)[tid] = z;
        reinterpret_cast<ushort4*>(yr + 2048)[tid] = z;
        return;
    }
    const int b = row / NQ_, qq = row - b * NQ_;
    const int prow = b*128 + qq;
    const float Linv = 1.0f / Lacc[prow*H_ + (tid >> 4)];
    float4 v = reinterpret_cast<const float4*>(ctxacc + (size_t)prow * D_)[tid];
    v.x *= Linv; v.y *= Linv; v.z *= Linv; v.w *= Linv;
    ushort4 hi, lo;
    hi.x = f2bf(v.x); hi.y = f2bf(v.y); hi.z = f2bf(v.z); hi.w = f2bf(v.w);
    lo.x = f2bf(v.x - bf2f(hi.x)); lo.y = f2bf(v.y - bf2f(hi.y));
    lo.z = f2bf(v.z - bf2f(hi.z)); lo.w = f2bf(v.w - bf2f(hi.w));
    reinterpret_cast<ushort4*>(yr)[tid]        = hi;
    reinterpret_cast<ushort4*>(yr + 1024)[tid] = lo;
    reinterpret_cast<ushort4*>(yr + 2048)[tid] = hi;
}

// ---------------------------------------------------------------------------
// out_w -> [hi | hi | lo] bf16, row stride 3072.
// ---------------------------------------------------------------------------
__global__ __launch_bounds__(256) void hilo_w_kernel(
    const float* __restrict__ w, unsigned short* __restrict__ y)
{
    const int row = blockIdx.x;   // 0..1023
    const int tid = threadIdx.x;
    const float4 v = reinterpret_cast<const float4*>(w + (size_t)row * D_)[tid];
    ushort4 hi, lo;
    hi.x = f2bf(v.x); hi.y = f2bf(v.y); hi.z = f2bf(v.z); hi.w = f2bf(v.w);
    lo.x = f2bf(v.x - bf2f(hi.x)); lo.y = f2bf(v.y - bf2f(hi.y));
    lo.z = f2bf(v.z - bf2f(hi.z)); lo.w = f2bf(v.w - bf2f(hi.w));
    unsigned short* yr = y + (size_t)row * 3072;
    reinterpret_cast<ushort4*>(yr)[tid]        = hi;
    reinterpret_cast<ushort4*>(yr + 1024)[tid] = hi;
    reinterpret_cast<ushort4*>(yr + 2048)[tid] = lo;
}

// ---------------------------------------------------------------------------
// Packed mask bits per (b, padded q row); all-masked row -> all-ones.
// ---------------------------------------------------------------------------
__global__ __launch_bounds__(256) void mpack_kernel(
    const int* __restrict__ mask, unsigned int* __restrict__ mp)
{
    const int qrow = blockIdx.x;   // 0..127
    const int b = blockIdx.y;
    const int tid = threadIdx.x;
    unsigned int word = 0;
    if (qrow < NQ_ && tid < 128) {
        const int4* mr = reinterpret_cast<const int4*>(
            mask + ((size_t)(b*NQ_ + qrow))*HW_ + tid*32);
        #pragma unroll
        for (int j = 0; j < 8; ++j) {
            const int4 v = mr[j];
            word |= (v.x!=0 ? 1u:0u) << (4*j);
            word |= (v.y!=0 ? 1u:0u) << (4*j+1);
            word |= (v.z!=0 ? 1u:0u) << (4*j+2);
            word |= (v.w!=0 ? 1u:0u) << (4*j+3);
        }
    }
    const int wany = __any(word != 0) ? 1 : 0;
    __shared__ int red[4];
    if ((tid & 63) == 0) red[tid >> 6] = wany;
    __syncthreads();
    const int hasany = red[0] | red[1] | red[2] | red[3];
    if (tid < 128)
        mp[((size_t)(b*128 + qrow))*128 + tid] = hasany ? word : 0xFFFFFFFFu;
}

// ---------------------------------------------------------------------------
// bf16 MFMA GEMM for K|V projection with fused V-transpose epilogue.
// C row m = b*4096+key, col n in [0,2048). bn<8 -> K half: kp[m][n] (bf16).
// bn>=8 -> V half written TRANSPOSED: vt[b*1024 + n-1024][key] (bf16).
// 128x128 tile, BK=32, 4 waves, global_load_lds, XOR-swizzled LDS.
// ---------------------------------------------------------------------------
__global__ __launch_bounds__(256) void gemm_kv_kernel(
    const unsigned short* __restrict__ A, const unsigned short* __restrict__ Wb,
    const float* __restrict__ bias, unsigned short* __restrict__ kp,
    unsigned short* __restrict__ vt)
{
    const int K = D_;
    __shared__ __align__(16) unsigned short As[4096];
    __shared__ __align__(16) unsigned short Bs[4096];

    const int tid  = threadIdx.x;
    const int wave = tid >> 6, lane = tid & 63;
    const int bn = blockIdx.x, bm = blockIdx.y;
    const int wm = (wave >> 1) * 64, wn = (wave & 1) * 64;

    const int r0  = tid >> 2;
    const int xs  = (r0 & 3) ^ ((r0 >> 2) & 3);
    const int kc  = (tid & 3) ^ xs;
    const unsigned short* ap0 = A  + (size_t)(bm*128 + r0      )*K + kc*8;
    const unsigned short* ap1 = A  + (size_t)(bm*128 + r0 + 64 )*K + kc*8;
    const unsigned short* bp0 = Wb + (size_t)(bn*128 + r0      )*K + kc*8;
    const unsigned short* bp1 = Wb + (size_t)(bn*128 + r0 + 64 )*K + kc*8;
    unsigned short* asd0 = As + wave*512;
    unsigned short* asd1 = As + 2048 + wave*512;
    unsigned short* bsd0 = Bs + wave*512;
    unsigned short* bsd1 = Bs + 2048 + wave*512;

    f32x4 acc[4][4];
    #pragma unroll
    for (int i = 0; i < 4; ++i)
        #pragma unroll
        for (int j = 0; j < 4; ++j)
            acc[i][j] = (f32x4){0.f, 0.f, 0.f, 0.f};

    const int lr = lane & 15, lq = lane >> 4;
    const int xl = (lr & 3) ^ ((lr >> 2) & 3);
    const int qs = (lq ^ xl) * 8;

    for (int kb = 0; kb < K; kb += 32) {
        gl2lds16(ap0, asd0); gl2lds16(ap1, asd1);
        gl2lds16(bp0, bsd0); gl2lds16(bp1, bsd1);
        ap0 += 32; ap1 += 32; bp0 += 32; bp1 += 32;
        __syncthreads();
        short8 af[4], bf[4];
        #pragma unroll
        for (int i = 0; i < 4; ++i) {
            af[i] = *reinterpret_cast<const short8*>(&As[(wm + i*16 + lr)*32 + qs]);
            bf[i] = *reinterpret_cast<const short8*>(&Bs[(wn + i*16 + lr)*32 + qs]);
        }
        #pragma unroll
        for (int i = 0; i < 4; ++i)
            #pragma unroll
            for (int j = 0; j < 4; ++j)
                acc[i][j] = __builtin_amdgcn_mfma_f32_16x16x32_bf16(
                    af[i], bf[j], acc[i][j], 0, 0, 0);
        __syncthreads();
    }

    const int row0 = bm*128 + wm + lq*4;       // m base for this lane
    const int col0 = bn*128 + wn + lr;         // n for this lane
    if (bn < 8) {
        // K half: kp[m][n]
        #pragma unroll
        for (int j = 0; j < 4; ++j) {
            const int n = col0 + j*16;
            const float bb = bias[n];
            #pragma unroll
            for (int i = 0; i < 4; ++i) {
                unsigned short* Cp = kp + (size_t)(row0 + i*16) * 1024 + n;
                #pragma unroll
                for (int r = 0; r < 4; ++r)
                    Cp[(size_t)r * 1024] = f2bf(acc[i][j][r] + bb);
            }
        }
    } else {
        // V half: vt[b*1024 + n-1024][key], key = m - b*4096
        const int b = bm >> 5;                 // 32 bm-tiles per batch
        const int key0base = row0 - b*4096;
        #pragma unroll
        for (int j = 0; j < 4; ++j) {
            const int n = col0 + j*16;
            const float bb = bias[n];
            unsigned short* vrow = vt + (size_t)(b*1024 + n - 1024) * HW_;
            #pragma unroll
            for (int i = 0; i < 4; ++i) {
                ushort4 o;
                o.x = f2bf(acc[i][j][0] + bb);
                o.y = f2bf(acc[i][j][1] + bb);
                o.z = f2bf(acc[i][j][2] + bb);
                o.w = f2bf(acc[i][j][3] + bb);
                *reinterpret_cast<ushort4*>(vrow + key0base + i*16) = o;
            }
        }
    }
}

// ---------------------------------------------------------------------------
// Split-K MFMA GEMM for skinny M: P[sk][m][n] = A[m, skKS:(sk+1)KS] @ W^T.
// ---------------------------------------------------------------------------
__global__ __launch_bounds__(256) void gemm_splitk_kernel(
    const unsigned short* __restrict__ A, const unsigned short* __restrict__ W,
    float* __restrict__ P, int K, int KS)
{
    __shared__ __align__(16) unsigned short As[2048];
    __shared__ __align__(16) unsigned short Bs[2048];
    const int tid = threadIdx.x;
    const int wave = tid >> 6, lane = tid & 63;
    const int lr = lane & 15, quad = lane >> 4;
    const int bn = blockIdx.x, bm = blockIdx.y, sk = blockIdx.z;

    const int r0 = tid >> 2;
    const int xs = (r0 & 3) ^ ((r0 >> 2) & 3);
    const int kc = (tid & 3) ^ xs;
    const unsigned short* ap = A + (size_t)(bm*64 + r0)*K + sk*KS + kc*8;
    const unsigned short* bp = W + (size_t)(bn*64 + r0)*K + sk*KS + kc*8;
    unsigned short* asd = As + wave*512;
    unsigned short* bsd = Bs + wave*512;

    f32x4 acc[4];
    #pragma unroll
    for (int j = 0; j < 4; ++j) acc[j] = (f32x4){0.f,0.f,0.f,0.f};

    const int arow = wave*16 + lr;
    const int xa = (arow & 3) ^ ((arow >> 2) & 3);
    const int aoff = (arow*4 + (quad ^ xa))*8;
    int boff[4];
    #pragma unroll
    for (int j = 0; j < 4; ++j) {
        const int brow = j*16 + lr;
        const int xb = (brow & 3) ^ ((brow >> 2) & 3);
        boff[j] = (brow*4 + (quad ^ xb))*8;
    }

    const int nsteps = KS >> 5;
    for (int s = 0; s < nsteps; ++s) {
        gl2lds16(ap, asd); gl2lds16(bp, bsd);
        ap += 32; bp += 32;
        __syncthreads();
        const short8 af = *reinterpret_cast<const short8*>(&As[aoff]);
        short8 bf[4];
        #pragma unroll
        for (int j = 0; j < 4; ++j)
            bf[j] = *reinterpret_cast<const short8*>(&Bs[boff[j]]);
        #pragma unroll
        for (int j = 0; j < 4; ++j)
            acc[j] = __builtin_amdgcn_mfma_f32_16x16x32_bf16(af, bf[j], acc[j], 0, 0, 0);
        __syncthreads();
    }

    float* Pb = P + ((size_t)sk*MP_ + bm*64)*1024 + bn*64;
    const int m0 = wave*16 + quad*4;
    #pragma unroll
    for (int j = 0; j < 4; ++j)
        #pragma unroll
        for (int r = 0; r < 4; ++r)
            Pb[(size_t)(m0 + r)*1024 + j*16 + lr] = acc[j][r];
}

// ---------------------------------------------------------------------------
// Reduce split-K partials + bias.
// ---------------------------------------------------------------------------
__global__ __launch_bounds__(256) void reduce_kernel(
    const float* __restrict__ P, const float* __restrict__ bias,
    float* __restrict__ Cout, int SK)
{
    const int i4 = blockIdx.x * 256 + threadIdx.x;
    const int c4 = i4 & 255;
    float4 s = reinterpret_cast<const float4*>(bias)[c4];
    for (int sk = 0; sk < SK; ++sk) {
        const float4 p = reinterpret_cast<const float4*>(P + (size_t)sk*MP_*1024)[i4];
        s.x += p.x; s.y += p.y; s.z += p.z; s.w += p.w;
    }
    reinterpret_cast<float4*>(Cout)[i4] = s;
}

// ---------------------------------------------------------------------------
// MFMA flash attention, fixed-max softmax, atomic accumulation.
// p = mask ? exp(s) : 0 (scale folded into Q staging; scores bounded so no
// overflow; mpack guarantees l > 0). Partials summed straight into
// ctxacc[b*128+q][1024] and Lacc[b*128+q][16] via atomicAdd (zeroed by host
// memset each launch). No combine pass.
// ---------------------------------------------------------------------------
__global__ __launch_bounds__(256) void flash_kernel(
    const float* __restrict__ qp, const unsigned short* __restrict__ kp,
    const unsigned short* __restrict__ vt, const unsigned int* __restrict__ mpack,
    float* __restrict__ ctxacc, float* __restrict__ Lacc)
{
    __shared__ __align__(16) unsigned char smem[49152];
    unsigned short* Ks  = (unsigned short*)smem;            // 16 KB
    unsigned short* Vts = (unsigned short*)(smem + 16384);  // 16 KB
    unsigned short* Qs  = (unsigned short*)(smem + 32768);  // 4608 B
    unsigned short* Ps  = (unsigned short*)(smem + 37376);  // 10240 B
    unsigned int*   MWs = (unsigned int*)  (smem + 47616);  // 512 B
    float*          mlW = (float*)         (smem + 48128);  // 512 B
    float*          Om  = (float*)smem;                     // merge alias

    const int tid = threadIdx.x;
    const int wave = tid >> 6, lane = tid & 63;
    const int lr = lane & 15, quad = lane >> 4;
    const int qt = blockIdx.x, h = blockIdx.y;
    const int b = blockIdx.z >> 3, ks = blockIdx.z & 7;
    const int kb0 = ks * KCH_;

    {   // stage Q (scaled by 1/sqrt(64) — exact pow2, folded into bf16)
        const int q = tid >> 3, dc = (tid & 7) * 8;
        const int qg = qt*QT_ + q;
        float4 v0 = make_float4(0.f,0.f,0.f,0.f), v1 = v0;
        if (qg < NQ_) {
            const float* src = qp + ((size_t)(b*NQ_ + qg))*D_ + h*HD_ + dc;
            v0 = *reinterpret_cast<const float4*>(src);
            v1 = *reinterpret_cast<const float4*>(src + 4);
        }
        ushort8v o;
        o[0]=f2bf(v0.x*0.125f); o[1]=f2bf(v0.y*0.125f);
        o[2]=f2bf(v0.z*0.125f); o[3]=f2bf(v0.w*0.125f);
        o[4]=f2bf(v1.x*0.125f); o[5]=f2bf(v1.y*0.125f);
        o[6]=f2bf(v1.z*0.125f); o[7]=f2bf(v1.w*0.125f);
        *reinterpret_cast<ushort8v*>(&Qs[q*72 + dc]) = o;
    }

    const unsigned short* kptr[4];
    const unsigned short* vptr[4];
    #pragma unroll
    for (int i = 0; i < 4; ++i) {
        const int s = i*256 + tid;
        const int key = s >> 3, jg = (s & 7) ^ (key & 7);
        kptr[i] = kp + ((size_t)(b*HW_) + kb0 + key)*1024 + h*HD_ + jg*8;
        const int d = s >> 4, js = s & 15, jg2 = js ^ (d & 15);
        vptr[i] = vt + ((size_t)(b*1024 + h*HD_ + d))*HW_ + kb0 + jg2*8;
    }

    int koff[2][2], voff[4];
    #pragma unroll
    for (int kj = 0; kj < 2; ++kj)
        #pragma unroll
        for (int ds = 0; ds < 2; ++ds) {
            const int key_l = wave*32 + kj*16 + lr;
            const int jg = ds*4 + quad;
            koff[kj][ds] = (key_l*8 + (jg ^ (key_l & 7))) * 8;
        }
    #pragma unroll
    for (int dj = 0; dj < 4; ++dj) {
        const int d_l = dj*16 + lr;
        const int jg = wave*4 + quad;
        voff[dj] = (d_l*16 + (jg ^ (d_l & 15))) * 8;
    }

    float lreg[8];
    #pragma unroll
    for (int i = 0; i < 8; ++i) lreg[i] = 0.f;
    f32x4 Ov[2][4];
    #pragma unroll
    for (int i = 0; i < 2; ++i)
        #pragma unroll
        for (int j = 0; j < 4; ++j)
            Ov[i][j] = (f32x4){0.f,0.f,0.f,0.f};

    for (int kt = 0; kt < 4; ++kt) {
        __syncthreads();
        #pragma unroll
        for (int i = 0; i < 4; ++i) {
            gl2lds16(kptr[i], Ks  + (i*256 + wave*64)*8);
            gl2lds16(vptr[i], Vts + (i*256 + wave*64)*8);
            kptr[i] += 128*1024; vptr[i] += 128;
        }
        if (tid < 128) {
            const int mw = tid >> 5, mq = tid & 31;
            MWs[mw*32 + mq] = mpack[((size_t)(b*128 + qt*QT_ + mq))*128 +
                                    (ks*16 + kt*4 + mw)];
        }
        __syncthreads();

        // ---- QK^T ----
        f32x4 S[2][2];
        #pragma unroll
        for (int i = 0; i < 2; ++i)
            #pragma unroll
            for (int kj = 0; kj < 2; ++kj)
                S[i][kj] = (f32x4){0.f,0.f,0.f,0.f};
        #pragma unroll
        for (int ds = 0; ds < 2; ++ds) {
            short8 aq[2], bk[2];
            aq[0] = *reinterpret_cast<const short8*>(&Qs[(     lr)*72 + ds*32 + quad*8]);
            aq[1] = *reinterpret_cast<const short8*>(&Qs[(16 + lr)*72 + ds*32 + quad*8]);
            bk[0] = *reinterpret_cast<const short8*>(&Ks[koff[0][ds]]);
            bk[1] = *reinterpret_cast<const short8*>(&Ks[koff[1][ds]]);
            #pragma unroll
            for (int i = 0; i < 2; ++i)
                #pragma unroll
                for (int kj = 0; kj < 2; ++kj)
                    S[i][kj] = __builtin_amdgcn_mfma_f32_16x16x32_bf16(
                        aq[i], bk[kj], S[i][kj], 0, 0, 0);
        }

        // ---- p = mask ? exp(s) : 0; per-lane l; P write (bf16, transposed) --
        #pragma unroll
        for (int i = 0; i < 2; ++i) {
            #pragma unroll
            for (int r = 0; r < 4; ++r) {
                const int q = i*16 + quad*4 + r;
                const unsigned int mw = MWs[wave*32 + q];
                const float p0 = ((mw >> lr) & 1u)        ? __expf(S[i][0][r]) : 0.f;
                const float p1 = ((mw >> (16 + lr)) & 1u) ? __expf(S[i][1][r]) : 0.f;
                lreg[i*4+r] += p0 + p1;
                const float p0n = __shfl_xor(p0, 1);
                const float p1n = __shfl_xor(p1, 1);
                if (!(lr & 1)) {
                    const unsigned int w0 = (unsigned)f2bf(p0) | ((unsigned)f2bf(p0n) << 16);
                    const unsigned int w1 = (unsigned)f2bf(p1) | ((unsigned)f2bf(p1n) << 16);
                    *reinterpret_cast<unsigned int*>(&Ps[wave*1280 + q*40 + lr])      = w0;
                    *reinterpret_cast<unsigned int*>(&Ps[wave*1280 + q*40 + 16 + lr]) = w1;
                }
            }
        }

        // ---- P @ V accumulate ----
        short8 pf[2], vf[4];
        #pragma unroll
        for (int i = 0; i < 2; ++i)
            pf[i] = *reinterpret_cast<const short8*>(&Ps[wave*1280 + (i*16+lr)*40 + quad*8]);
        #pragma unroll
        for (int dj = 0; dj < 4; ++dj)
            vf[dj] = *reinterpret_cast<const short8*>(&Vts[voff[dj]]);
        #pragma unroll
        for (int i = 0; i < 2; ++i)
            #pragma unroll
            for (int dj = 0; dj < 4; ++dj)
                Ov[i][dj] = __builtin_amdgcn_mfma_f32_16x16x32_bf16(
                    pf[i], vf[dj], Ov[i][dj], 0, 0, 0);
    }

    // ---- block merge (4 waves) then atomic accumulation ----
    __syncthreads();
    #pragma unroll
    for (int i = 0; i < 2; ++i)
        #pragma unroll
        for (int r = 0; r < 4; ++r) {
            float l = lreg[i*4+r];
            #pragma unroll
            for (int o = 1; o < 16; o <<= 1) l += __shfl_xor(l, o);
            if (lr == 0) mlW[wave*32 + i*16 + quad*4 + r] = l;
        }
    #pragma unroll
    for (int i = 0; i < 2; ++i)
        #pragma unroll
        for (int dj = 0; dj < 4; ++dj)
            #pragma unroll
            for (int r = 0; r < 4; ++r) {
                const int q = i*16 + quad*4 + r;
                Om[wave*2112 + q*66 + dj*16 + lr] = Ov[i][dj][r];
            }
    __syncthreads();
    {
        const int q = tid >> 3, dc = (tid & 7) * 8;
        float L = 0.f;
        #pragma unroll
        for (int w = 0; w < 4; ++w) L += mlW[w*32 + q];
        float os[8] = {};
        #pragma unroll
        for (int w = 0; w < 4; ++w)
            #pragma unroll
            for (int j = 0; j < 8; ++j)
                os[j] += Om[w*2112 + q*66 + dc + j];
        const int prow = b*128 + qt*QT_ + q;
        float* dst = ctxacc + (size_t)prow * D_ + h*HD_ + dc;
        #pragma unroll
        for (int j = 0; j < 8; ++j) atomicAdd(dst + j, os[j]);
        if ((tid & 7) == 0) atomicAdd(&Lacc[prow*H_ + h], L);
    }
}

// ---------------------------------------------------------------------------
// Workspace (bytes):
//   qp       @ 0           (1,638,400)
//   mpack    @ 1,638,400   (262,144)
//   wfull_bf @ 1,900,544   (6,291,456)
//   qn_bf    @ 8,192,000   (1,048,576)
//   ctx_cat  @ 9,240,576   (3,145,728)
//   wout_cat @ 12,386,304  (6,291,456)
//   P        @ 18,677,760  (16,777,216)
//   ctxacc   @ 35,454,976  (2,097,152)   512x1024 f32 (memset 0 per launch)
//   Lacc     @ 37,552,128  (32,768)      512x16  f32 (memset 0 per launch)
//   kvn_bf   @ 37,584,896  (33,554,432)
//   kp       @ 71,139,328  (33,554,432)  bf16 [16384][1024]
//   vt       @ 104,693,760 (33,554,432)  bf16 [4096][4096]  -> ~138 MB
// ---------------------------------------------------------------------------
extern "C" void kernel_launch(void* const* d_in, const int* in_sizes, int n_in,
                              void* d_out, int out_size, void* d_ws, size_t ws_size,
                              hipStream_t stream)
{
    const float* q     = (const float*)d_in[0];
    const float* kv    = (const float*)d_in[1];
    const int*   mask  = (const int*)  d_in[2];
    const float* in_w  = (const float*)d_in[3];
    const float* in_b  = (const float*)d_in[4];
    const float* out_w = (const float*)d_in[5];
    const float* out_b = (const float*)d_in[6];
    const float* g_q   = (const float*)d_in[7];
    const float* b_q   = (const float*)d_in[8];
    const float* g_kv  = (const float*)d_in[9];
    const float* b_kv  = (const float*)d_in[10];
    float* out = (float*)d_out;

    char* ws = (char*)d_ws;
    float*          qp       = (float*)         (ws + 0);
    unsigned int*   mpackp   = (unsigned int*)  (ws + 1638400);
    unsigned short* wfull_bf = (unsigned short*)(ws + 1900544);
    unsigned short* qn_bf    = (unsigned short*)(ws + 8192000);
    unsigned short* ctx_cat  = (unsigned short*)(ws + 9240576);
    unsigned short* wout_cat = (unsigned short*)(ws + 12386304);
    float*          P        = (float*)         (ws + 18677760);
    float*          ctxacc   = (float*)         (ws + 35454976);
    float*          Lacc     = (float*)         (ws + 37552128);
    unsigned short* kvn_bf   = (unsigned short*)(ws + 37584896);
    unsigned short* kp       = (unsigned short*)(ws + 71139328);
    unsigned short* vt       = (unsigned short*)(ws + 104693760);

    // --- prep ---
    hipMemsetAsync(ctxacc, 0, (size_t)MP_ * D_ * 4, stream);
    hipMemsetAsync(Lacc,   0, (size_t)MP_ * H_ * 4, stream);
    mpack_kernel<<<dim3(128, B_), 256, 0, stream>>>(mask, mpackp);
    wconv_kernel<<<3*D_*D_/4/256, 256, 0, stream>>>(in_w, wfull_bf);
    ln_bf16_kernel<<<B_*HW_/4, 256, 0, stream>>>(kv, g_kv, b_kv, kvn_bf, B_*HW_);
    ln_bf16_kernel<<<MP_/4, 256, 0, stream>>>(q, g_q, b_q, qn_bf, B_*NQ_);

    // --- Q projection: split-K MFMA + reduce ---
    gemm_splitk_kernel<<<dim3(D_/64, MP_/64, 8), 256, 0, stream>>>(
        qn_bf, wfull_bf, P, D_, 128);
    reduce_kernel<<<B_*NQ_*D_/4/256, 256, 0, stream>>>(P, in_b, qp, 8);

    // --- K|V projection: bf16 MFMA; K -> kp, V -> vt (fused transpose) ---
    gemm_kv_kernel<<<dim3(16, B_*HW_/128), 256, 0, stream>>>(
        kvn_bf, wfull_bf + (size_t)D_*D_, in_b + D_, kp, vt);

    // --- MFMA flash attention (atomic accumulate; no combine pass) ---
    flash_kernel<<<dim3(4, H_, B_*NCH_), 256, 0, stream>>>(
        qp, kp, vt, mpackp, ctxacc, Lacc);

    // --- Output projection: O/L + hi/lo split, split-K MFMA, reduce ---
    hilo_a_kernel<<<MP_, 256, 0, stream>>>(ctxacc, Lacc, ctx_cat);
    hilo_w_kernel<<<D_, 256, 0, stream>>>(out_w, wout_cat);
    gemm_splitk_kernel<<<dim3(D_/64, MP_/64, 8), 256, 0, stream>>>(
        ctx_cat, wout_cat, P, 3*D_, 384);
    reduce_kernel<<<B_*NQ_*D_/4/256, 256, 0, stream>>>(P, out_b, out, 8);
}

// Round 8
// 330.925 us; speedup vs baseline: 1.2926x; 1.2926x over previous
//
#include <hip/hip_runtime.h>
#include <math.h>
#include <stdint.h>

#define B_    4
#define NQ_   100
#define HW_   4096
#define D_    1024
#define H_    16
#define HD_   64
#define NCH_  8          // key chunks per (b,h) for split-K flash
#define KCH_  (HW_/NCH_) // 512 keys per chunk
#define QT_   32         // queries per tile (4 tiles cover 100, padded)
#define MP_   512        // padded M for small GEMMs (400 -> 512)

typedef __attribute__((ext_vector_type(8))) short short8;
typedef __attribute__((ext_vector_type(8))) unsigned short ushort8v;
typedef __attribute__((ext_vector_type(4))) float f32x4;

// fp32 -> bf16 RNE
__device__ __forceinline__ unsigned short f2bf(float f) {
    unsigned int u = __float_as_uint(f);
    u += 0x7fffu + ((u >> 16) & 1u);
    return (unsigned short)(u >> 16);
}
__device__ __forceinline__ float bf2f(unsigned short h) {
    return __uint_as_float(((unsigned int)h) << 16);
}

// async global->LDS 16B
__device__ __forceinline__ void gl2lds16(const void* g, void* l) {
    typedef __attribute__((address_space(1))) unsigned int gu32;
    typedef __attribute__((address_space(3))) unsigned int lu32;
    __builtin_amdgcn_global_load_lds(
        reinterpret_cast<gu32*>(reinterpret_cast<uintptr_t>(g)),
        reinterpret_cast<lu32*>(reinterpret_cast<uintptr_t>(l)),
        16, 0, 0);
}

// ---------------------------------------------------------------------------
// LayerNorm + bf16: wave-per-row (no block barriers). 4 rows per 256-block.
// Rows >= real_rows write zeros (padding).
// ---------------------------------------------------------------------------
__global__ __launch_bounds__(256) void ln_bf16_kernel(
    const float* __restrict__ x, const float* __restrict__ g,
    const float* __restrict__ be, unsigned short* __restrict__ y, int real_rows)
{
    const int wv = threadIdx.x >> 6, lane = threadIdx.x & 63;
    const int row = blockIdx.x * 4 + wv;
    unsigned short* yr = y + (size_t)row * D_;
    if (row >= real_rows) {
        #pragma unroll
        for (int k = 0; k < 4; ++k)
            *reinterpret_cast<ushort4*>(yr + lane*4 + k*256) = make_ushort4(0,0,0,0);
        return;
    }
    const float* xr = x + (size_t)row * D_;
    float4 v[4];
    float s = 0.f, ss = 0.f;
    #pragma unroll
    for (int k = 0; k < 4; ++k) {
        v[k] = *reinterpret_cast<const float4*>(xr + lane*4 + k*256);
        s  += v[k].x + v[k].y + v[k].z + v[k].w;
        ss += v[k].x*v[k].x + v[k].y*v[k].y + v[k].z*v[k].z + v[k].w*v[k].w;
    }
    #pragma unroll
    for (int o = 1; o < 64; o <<= 1) {
        s  += __shfl_xor(s,  o);
        ss += __shfl_xor(ss, o);
    }
    const float mu = s * (1.0f / D_);
    const float rs = rsqrtf(ss * (1.0f / D_) - mu*mu + 1e-5f);
    #pragma unroll
    for (int k = 0; k < 4; ++k) {
        const float4 gg = *reinterpret_cast<const float4*>(g  + lane*4 + k*256);
        const float4 bb = *reinterpret_cast<const float4*>(be + lane*4 + k*256);
        ushort4 o;
        o.x = f2bf((v[k].x - mu) * rs * gg.x + bb.x);
        o.y = f2bf((v[k].y - mu) * rs * gg.y + bb.y);
        o.z = f2bf((v[k].z - mu) * rs * gg.z + bb.z);
        o.w = f2bf((v[k].w - mu) * rs * gg.w + bb.w);
        *reinterpret_cast<ushort4*>(yr + lane*4 + k*256) = o;
    }
}

// ---------------------------------------------------------------------------
// fp32 -> bf16 convert (flat float4 per thread)
// ---------------------------------------------------------------------------
__global__ __launch_bounds__(256) void wconv_kernel(
    const float* __restrict__ w, unsigned short* __restrict__ wb)
{
    const int i = blockIdx.x * 256 + threadIdx.x;
    const float4 v = reinterpret_cast<const float4*>(w)[i];
    ushort4 o;
    o.x = f2bf(v.x); o.y = f2bf(v.y); o.z = f2bf(v.z); o.w = f2bf(v.w);
    reinterpret_cast<ushort4*>(wb)[i] = o;
}

// ---------------------------------------------------------------------------
// ctx -> [hi | lo | hi] bf16, row stride 3072, pad rows (>=400) zeroed.
// ---------------------------------------------------------------------------
__global__ __launch_bounds__(256) void hilo_a_kernel(
    const float* __restrict__ x, unsigned short* __restrict__ y)
{
    const int row = blockIdx.x;   // 0..511
    const int tid = threadIdx.x;
    unsigned short* yr = y + (size_t)row * 3072;
    if (row >= B_*NQ_) {
        const ushort4 z = make_ushort4(0,0,0,0);
        reinterpret_cast<ushort4*>(yr)[tid]        = z;
        reinterpret_cast<ushort4*>(yr + 1024)[tid] = z;
        reinterpret_cast<ushort4*>(yr + 2048)[tid] = z;
        return;
    }
    const float4 v = reinterpret_cast<const float4*>(x + (size_t)row * D_)[tid];
    ushort4 hi, lo;
    hi.x = f2bf(v.x); hi.y = f2bf(v.y); hi.z = f2bf(v.z); hi.w = f2bf(v.w);
    lo.x = f2bf(v.x - bf2f(hi.x)); lo.y = f2bf(v.y - bf2f(hi.y));
    lo.z = f2bf(v.z - bf2f(hi.z)); lo.w = f2bf(v.w - bf2f(hi.w));
    reinterpret_cast<ushort4*>(yr)[tid]        = hi;
    reinterpret_cast<ushort4*>(yr + 1024)[tid] = lo;
    reinterpret_cast<ushort4*>(yr + 2048)[tid] = hi;
}

// ---------------------------------------------------------------------------
// out_w -> [hi | hi | lo] bf16, row stride 3072.
// ---------------------------------------------------------------------------
__global__ __launch_bounds__(256) void hilo_w_kernel(
    const float* __restrict__ w, unsigned short* __restrict__ y)
{
    const int row = blockIdx.x;   // 0..1023
    const int tid = threadIdx.x;
    const float4 v = reinterpret_cast<const float4*>(w + (size_t)row * D_)[tid];
    ushort4 hi, lo;
    hi.x = f2bf(v.x); hi.y = f2bf(v.y); hi.z = f2bf(v.z); hi.w = f2bf(v.w);
    lo.x = f2bf(v.x - bf2f(hi.x)); lo.y = f2bf(v.y - bf2f(hi.y));
    lo.z = f2bf(v.z - bf2f(hi.z)); lo.w = f2bf(v.w - bf2f(hi.w));
    unsigned short* yr = y + (size_t)row * 3072;
    reinterpret_cast<ushort4*>(yr)[tid]        = hi;
    reinterpret_cast<ushort4*>(yr + 1024)[tid] = hi;
    reinterpret_cast<ushort4*>(yr + 2048)[tid] = lo;
}

// ---------------------------------------------------------------------------
// Packed mask bits per (b, padded q row); all-masked row -> all-ones.
// ---------------------------------------------------------------------------
__global__ __launch_bounds__(256) void mpack_kernel(
    const int* __restrict__ mask, unsigned int* __restrict__ mp)
{
    const int qrow = blockIdx.x;   // 0..127
    const int b = blockIdx.y;
    const int tid = threadIdx.x;
    unsigned int word = 0;
    if (qrow < NQ_ && tid < 128) {
        const int4* mr = reinterpret_cast<const int4*>(
            mask + ((size_t)(b*NQ_ + qrow))*HW_ + tid*32);
        #pragma unroll
        for (int j = 0; j < 8; ++j) {
            const int4 v = mr[j];
            word |= (v.x!=0 ? 1u:0u) << (4*j);
            word |= (v.y!=0 ? 1u:0u) << (4*j+1);
            word |= (v.z!=0 ? 1u:0u) << (4*j+2);
            word |= (v.w!=0 ? 1u:0u) << (4*j+3);
        }
    }
    const int wany = __any(word != 0) ? 1 : 0;
    __shared__ int red[4];
    if ((tid & 63) == 0) red[tid >> 6] = wany;
    __syncthreads();
    const int hasany = red[0] | red[1] | red[2] | red[3];
    if (tid < 128)
        mp[((size_t)(b*128 + qrow))*128 + tid] = hasany ? word : 0xFFFFFFFFu;
}

// ---------------------------------------------------------------------------
// bf16 MFMA GEMM for K|V projection with fused V-transpose epilogue.
// bn<8 -> K half: kp[m][n] (bf16). bn>=8 -> V half written TRANSPOSED:
// vt[b*1024 + n-1024][key] (bf16). 128x128 tile, BK=32, global_load_lds.
// ---------------------------------------------------------------------------
__global__ __launch_bounds__(256) void gemm_kv_kernel(
    const unsigned short* __restrict__ A, const unsigned short* __restrict__ Wb,
    const float* __restrict__ bias, unsigned short* __restrict__ kp,
    unsigned short* __restrict__ vt)
{
    const int K = D_;
    __shared__ __align__(16) unsigned short As[4096];
    __shared__ __align__(16) unsigned short Bs[4096];

    const int tid  = threadIdx.x;
    const int wave = tid >> 6, lane = tid & 63;
    const int bn = blockIdx.x, bm = blockIdx.y;
    const int wm = (wave >> 1) * 64, wn = (wave & 1) * 64;

    const int r0  = tid >> 2;
    const int xs  = (r0 & 3) ^ ((r0 >> 2) & 3);
    const int kc  = (tid & 3) ^ xs;
    const unsigned short* ap0 = A  + (size_t)(bm*128 + r0      )*K + kc*8;
    const unsigned short* ap1 = A  + (size_t)(bm*128 + r0 + 64 )*K + kc*8;
    const unsigned short* bp0 = Wb + (size_t)(bn*128 + r0      )*K + kc*8;
    const unsigned short* bp1 = Wb + (size_t)(bn*128 + r0 + 64 )*K + kc*8;
    unsigned short* asd0 = As + wave*512;
    unsigned short* asd1 = As + 2048 + wave*512;
    unsigned short* bsd0 = Bs + wave*512;
    unsigned short* bsd1 = Bs + 2048 + wave*512;

    f32x4 acc[4][4];
    #pragma unroll
    for (int i = 0; i < 4; ++i)
        #pragma unroll
        for (int j = 0; j < 4; ++j)
            acc[i][j] = (f32x4){0.f, 0.f, 0.f, 0.f};

    const int lr = lane & 15, lq = lane >> 4;
    const int xl = (lr & 3) ^ ((lr >> 2) & 3);
    const int qs = (lq ^ xl) * 8;

    for (int kb = 0; kb < K; kb += 32) {
        gl2lds16(ap0, asd0); gl2lds16(ap1, asd1);
        gl2lds16(bp0, bsd0); gl2lds16(bp1, bsd1);
        ap0 += 32; ap1 += 32; bp0 += 32; bp1 += 32;
        __syncthreads();
        short8 af[4], bf[4];
        #pragma unroll
        for (int i = 0; i < 4; ++i) {
            af[i] = *reinterpret_cast<const short8*>(&As[(wm + i*16 + lr)*32 + qs]);
            bf[i] = *reinterpret_cast<const short8*>(&Bs[(wn + i*16 + lr)*32 + qs]);
        }
        #pragma unroll
        for (int i = 0; i < 4; ++i)
            #pragma unroll
            for (int j = 0; j < 4; ++j)
                acc[i][j] = __builtin_amdgcn_mfma_f32_16x16x32_bf16(
                    af[i], bf[j], acc[i][j], 0, 0, 0);
        __syncthreads();
    }

    const int row0 = bm*128 + wm + lq*4;       // m base for this lane
    const int col0 = bn*128 + wn + lr;         // n for this lane
    if (bn < 8) {
        // K half: kp[m][n]
        #pragma unroll
        for (int j = 0; j < 4; ++j) {
            const int n = col0 + j*16;
            const float bb = bias[n];
            #pragma unroll
            for (int i = 0; i < 4; ++i) {
                unsigned short* Cp = kp + (size_t)(row0 + i*16) * 1024 + n;
                #pragma unroll
                for (int r = 0; r < 4; ++r)
                    Cp[(size_t)r * 1024] = f2bf(acc[i][j][r] + bb);
            }
        }
    } else {
        // V half: vt[b*1024 + n-1024][key], key = m - b*4096
        const int b = bm >> 5;                 // 32 bm-tiles per batch
        const int key0base = row0 - b*4096;
        #pragma unroll
        for (int j = 0; j < 4; ++j) {
            const int n = col0 + j*16;
            const float bb = bias[n];
            unsigned short* vrow = vt + (size_t)(b*1024 + n - 1024) * HW_;
            #pragma unroll
            for (int i = 0; i < 4; ++i) {
                ushort4 o;
                o.x = f2bf(acc[i][j][0] + bb);
                o.y = f2bf(acc[i][j][1] + bb);
                o.z = f2bf(acc[i][j][2] + bb);
                o.w = f2bf(acc[i][j][3] + bb);
                *reinterpret_cast<ushort4*>(vrow + key0base + i*16) = o;
            }
        }
    }
}

// ---------------------------------------------------------------------------
// Split-K MFMA GEMM for skinny M: P[sk][m][n] = A[m, skKS:(sk+1)KS] @ W^T.
// ---------------------------------------------------------------------------
__global__ __launch_bounds__(256) void gemm_splitk_kernel(
    const unsigned short* __restrict__ A, const unsigned short* __restrict__ W,
    float* __restrict__ P, int K, int KS)
{
    __shared__ __align__(16) unsigned short As[2048];
    __shared__ __align__(16) unsigned short Bs[2048];
    const int tid = threadIdx.x;
    const int wave = tid >> 6, lane = tid & 63;
    const int lr = lane & 15, quad = lane >> 4;
    const int bn = blockIdx.x, bm = blockIdx.y, sk = blockIdx.z;

    const int r0 = tid >> 2;
    const int xs = (r0 & 3) ^ ((r0 >> 2) & 3);
    const int kc = (tid & 3) ^ xs;
    const unsigned short* ap = A + (size_t)(bm*64 + r0)*K + sk*KS + kc*8;
    const unsigned short* bp = W + (size_t)(bn*64 + r0)*K + sk*KS + kc*8;
    unsigned short* asd = As + wave*512;
    unsigned short* bsd = Bs + wave*512;

    f32x4 acc[4];
    #pragma unroll
    for (int j = 0; j < 4; ++j) acc[j] = (f32x4){0.f,0.f,0.f,0.f};

    const int arow = wave*16 + lr;
    const int xa = (arow & 3) ^ ((arow >> 2) & 3);
    const int aoff = (arow*4 + (quad ^ xa))*8;
    int boff[4];
    #pragma unroll
    for (int j = 0; j < 4; ++j) {
        const int brow = j*16 + lr;
        const int xb = (brow & 3) ^ ((brow >> 2) & 3);
        boff[j] = (brow*4 + (quad ^ xb))*8;
    }

    const int nsteps = KS >> 5;
    for (int s = 0; s < nsteps; ++s) {
        gl2lds16(ap, asd); gl2lds16(bp, bsd);
        ap += 32; bp += 32;
        __syncthreads();
        const short8 af = *reinterpret_cast<const short8*>(&As[aoff]);
        short8 bf[4];
        #pragma unroll
        for (int j = 0; j < 4; ++j)
            bf[j] = *reinterpret_cast<const short8*>(&Bs[boff[j]]);
        #pragma unroll
        for (int j = 0; j < 4; ++j)
            acc[j] = __builtin_amdgcn_mfma_f32_16x16x32_bf16(af, bf[j], acc[j], 0, 0, 0);
        __syncthreads();
    }

    float* Pb = P + ((size_t)sk*MP_ + bm*64)*1024 + bn*64;
    const int m0 = wave*16 + quad*4;
    #pragma unroll
    for (int j = 0; j < 4; ++j)
        #pragma unroll
        for (int r = 0; r < 4; ++r)
            Pb[(size_t)(m0 + r)*1024 + j*16 + lr] = acc[j][r];
}

// ---------------------------------------------------------------------------
// Reduce split-K partials + bias.
// ---------------------------------------------------------------------------
__global__ __launch_bounds__(256) void reduce_kernel(
    const float* __restrict__ P, const float* __restrict__ bias,
    float* __restrict__ Cout, int SK)
{
    const int i4 = blockIdx.x * 256 + threadIdx.x;
    const int c4 = i4 & 255;
    float4 s = reinterpret_cast<const float4*>(bias)[c4];
    for (int sk = 0; sk < SK; ++sk) {
        const float4 p = reinterpret_cast<const float4*>(P + (size_t)sk*MP_*1024)[i4];
        s.x += p.x; s.y += p.y; s.z += p.z; s.w += p.w;
    }
    reinterpret_cast<float4*>(Cout)[i4] = s;
}

// ---------------------------------------------------------------------------
// MFMA flash attention, fixed-max softmax, split-K partial outputs.
// p = mask ? exp(s) : 0 (scale folded into Q staging; scores bounded, no
// overflow; mpack guarantees l > 0). Block writes plain-sum partials
// (partO, partL); combine_kernel sums the 8 chunks and divides.
// NOTE (R7 post-mortem): do NOT accumulate via global atomicAdd here —
// cross-XCD RMW fanout multiplied WRITE_SIZE ~8x and cost +115 µs.
// ---------------------------------------------------------------------------
__global__ __launch_bounds__(256) void flash_kernel(
    const float* __restrict__ qp, const unsigned short* __restrict__ kp,
    const unsigned short* __restrict__ vt, const unsigned int* __restrict__ mpack,
    float* __restrict__ partO, float* __restrict__ partL)
{
    __shared__ __align__(16) unsigned char smem[49152];
    unsigned short* Ks  = (unsigned short*)smem;            // 16 KB
    unsigned short* Vts = (unsigned short*)(smem + 16384);  // 16 KB
    unsigned short* Qs  = (unsigned short*)(smem + 32768);  // 4608 B
    unsigned short* Ps  = (unsigned short*)(smem + 37376);  // 10240 B
    unsigned int*   MWs = (unsigned int*)  (smem + 47616);  // 512 B
    float*          mlW = (float*)         (smem + 48128);  // 512 B
    float*          Om  = (float*)smem;                     // merge alias

    const int tid = threadIdx.x;
    const int wave = tid >> 6, lane = tid & 63;
    const int lr = lane & 15, quad = lane >> 4;
    const int qt = blockIdx.x, h = blockIdx.y;
    const int b = blockIdx.z >> 3, ks = blockIdx.z & 7;
    const int kb0 = ks * KCH_;

    {   // stage Q (scaled by 1/sqrt(64) — exact pow2, folded into bf16)
        const int q = tid >> 3, dc = (tid & 7) * 8;
        const int qg = qt*QT_ + q;
        float4 v0 = make_float4(0.f,0.f,0.f,0.f), v1 = v0;
        if (qg < NQ_) {
            const float* src = qp + ((size_t)(b*NQ_ + qg))*D_ + h*HD_ + dc;
            v0 = *reinterpret_cast<const float4*>(src);
            v1 = *reinterpret_cast<const float4*>(src + 4);
        }
        ushort8v o;
        o[0]=f2bf(v0.x*0.125f); o[1]=f2bf(v0.y*0.125f);
        o[2]=f2bf(v0.z*0.125f); o[3]=f2bf(v0.w*0.125f);
        o[4]=f2bf(v1.x*0.125f); o[5]=f2bf(v1.y*0.125f);
        o[6]=f2bf(v1.z*0.125f); o[7]=f2bf(v1.w*0.125f);
        *reinterpret_cast<ushort8v*>(&Qs[q*72 + dc]) = o;
    }

    const unsigned short* kptr[4];
    const unsigned short* vptr[4];
    #pragma unroll
    for (int i = 0; i < 4; ++i) {
        const int s = i*256 + tid;
        const int key = s >> 3, jg = (s & 7) ^ (key & 7);
        kptr[i] = kp + ((size_t)(b*HW_) + kb0 + key)*1024 + h*HD_ + jg*8;
        const int d = s >> 4, js = s & 15, jg2 = js ^ (d & 15);
        vptr[i] = vt + ((size_t)(b*1024 + h*HD_ + d))*HW_ + kb0 + jg2*8;
    }

    int koff[2][2], voff[4];
    #pragma unroll
    for (int kj = 0; kj < 2; ++kj)
        #pragma unroll
        for (int ds = 0; ds < 2; ++ds) {
            const int key_l = wave*32 + kj*16 + lr;
            const int jg = ds*4 + quad;
            koff[kj][ds] = (key_l*8 + (jg ^ (key_l & 7))) * 8;
        }
    #pragma unroll
    for (int dj = 0; dj < 4; ++dj) {
        const int d_l = dj*16 + lr;
        const int jg = wave*4 + quad;
        voff[dj] = (d_l*16 + (jg ^ (d_l & 15))) * 8;
    }

    float lreg[8];
    #pragma unroll
    for (int i = 0; i < 8; ++i) lreg[i] = 0.f;
    f32x4 Ov[2][4];
    #pragma unroll
    for (int i = 0; i < 2; ++i)
        #pragma unroll
        for (int j = 0; j < 4; ++j)
            Ov[i][j] = (f32x4){0.f,0.f,0.f,0.f};

    for (int kt = 0; kt < 4; ++kt) {
        __syncthreads();
        #pragma unroll
        for (int i = 0; i < 4; ++i) {
            gl2lds16(kptr[i], Ks  + (i*256 + wave*64)*8);
            gl2lds16(vptr[i], Vts + (i*256 + wave*64)*8);
            kptr[i] += 128*1024; vptr[i] += 128;
        }
        if (tid < 128) {
            const int mw = tid >> 5, mq = tid & 31;
            MWs[mw*32 + mq] = mpack[((size_t)(b*128 + qt*QT_ + mq))*128 +
                                    (ks*16 + kt*4 + mw)];
        }
        __syncthreads();

        // ---- QK^T ----
        f32x4 S[2][2];
        #pragma unroll
        for (int i = 0; i < 2; ++i)
            #pragma unroll
            for (int kj = 0; kj < 2; ++kj)
                S[i][kj] = (f32x4){0.f,0.f,0.f,0.f};
        #pragma unroll
        for (int ds = 0; ds < 2; ++ds) {
            short8 aq[2], bk[2];
            aq[0] = *reinterpret_cast<const short8*>(&Qs[(     lr)*72 + ds*32 + quad*8]);
            aq[1] = *reinterpret_cast<const short8*>(&Qs[(16 + lr)*72 + ds*32 + quad*8]);
            bk[0] = *reinterpret_cast<const short8*>(&Ks[koff[0][ds]]);
            bk[1] = *reinterpret_cast<const short8*>(&Ks[koff[1][ds]]);
            #pragma unroll
            for (int i = 0; i < 2; ++i)
                #pragma unroll
                for (int kj = 0; kj < 2; ++kj)
                    S[i][kj] = __builtin_amdgcn_mfma_f32_16x16x32_bf16(
                        aq[i], bk[kj], S[i][kj], 0, 0, 0);
        }

        // ---- p = mask ? exp(s) : 0; per-lane l; P write (bf16, transposed) --
        #pragma unroll
        for (int i = 0; i < 2; ++i) {
            #pragma unroll
            for (int r = 0; r < 4; ++r) {
                const int q = i*16 + quad*4 + r;
                const unsigned int mw = MWs[wave*32 + q];
                const float p0 = ((mw >> lr) & 1u)        ? __expf(S[i][0][r]) : 0.f;
                const float p1 = ((mw >> (16 + lr)) & 1u) ? __expf(S[i][1][r]) : 0.f;
                lreg[i*4+r] += p0 + p1;
                const float p0n = __shfl_xor(p0, 1);
                const float p1n = __shfl_xor(p1, 1);
                if (!(lr & 1)) {
                    const unsigned int w0 = (unsigned)f2bf(p0) | ((unsigned)f2bf(p0n) << 16);
                    const unsigned int w1 = (unsigned)f2bf(p1) | ((unsigned)f2bf(p1n) << 16);
                    *reinterpret_cast<unsigned int*>(&Ps[wave*1280 + q*40 + lr])      = w0;
                    *reinterpret_cast<unsigned int*>(&Ps[wave*1280 + q*40 + 16 + lr]) = w1;
                }
            }
        }

        // ---- P @ V accumulate ----
        short8 pf[2], vf[4];
        #pragma unroll
        for (int i = 0; i < 2; ++i)
            pf[i] = *reinterpret_cast<const short8*>(&Ps[wave*1280 + (i*16+lr)*40 + quad*8]);
        #pragma unroll
        for (int dj = 0; dj < 4; ++dj)
            vf[dj] = *reinterpret_cast<const short8*>(&Vts[voff[dj]]);
        #pragma unroll
        for (int i = 0; i < 2; ++i)
            #pragma unroll
            for (int dj = 0; dj < 4; ++dj)
                Ov[i][dj] = __builtin_amdgcn_mfma_f32_16x16x32_bf16(
                    pf[i], vf[dj], Ov[i][dj], 0, 0, 0);
    }

    // ---- block merge (4 waves) then partial store ----
    __syncthreads();
    #pragma unroll
    for (int i = 0; i < 2; ++i)
        #pragma unroll
        for (int r = 0; r < 4; ++r) {
            float l = lreg[i*4+r];
            #pragma unroll
            for (int o = 1; o < 16; o <<= 1) l += __shfl_xor(l, o);
            if (lr == 0) mlW[wave*32 + i*16 + quad*4 + r] = l;
        }
    #pragma unroll
    for (int i = 0; i < 2; ++i)
        #pragma unroll
        for (int dj = 0; dj < 4; ++dj)
            #pragma unroll
            for (int r = 0; r < 4; ++r) {
                const int q = i*16 + quad*4 + r;
                Om[wave*2112 + q*66 + dj*16 + lr] = Ov[i][dj][r];
            }
    __syncthreads();
    {
        const int q = tid >> 3, dc = (tid & 7) * 8;
        float L = 0.f;
        #pragma unroll
        for (int w = 0; w < 4; ++w) L += mlW[w*32 + q];
        float os[8] = {};
        #pragma unroll
        for (int w = 0; w < 4; ++w)
            #pragma unroll
            for (int j = 0; j < 8; ++j)
                os[j] += Om[w*2112 + q*66 + dc + j];
        const size_t pr = (((size_t)(b*H_ + h))*NCH_ + ks)*128 + qt*QT_ + q;
        *reinterpret_cast<float4*>(&partO[pr*HD_ + dc])     = make_float4(os[0],os[1],os[2],os[3]);
        *reinterpret_cast<float4*>(&partO[pr*HD_ + dc + 4]) = make_float4(os[4],os[5],os[6],os[7]);
        if ((tid & 7) == 0) partL[pr] = L;
    }
}

// ---------------------------------------------------------------------------
// Merge split-K chunk partials: ctx = (sum O_i) / (sum L_i).
// ---------------------------------------------------------------------------
__global__ __launch_bounds__(64) void combine_kernel(
    const float* __restrict__ partO, const float* __restrict__ partL,
    float* __restrict__ ctx)
{
    const int d = threadIdx.x;
    const int qi = blockIdx.x, h = blockIdx.y, b = blockIdx.z;
    const size_t base = ((size_t)(b*H_ + h)) * NCH_ * 128;
    float L = 0.f, O = 0.f;
    #pragma unroll
    for (int i = 0; i < NCH_; ++i) {
        const size_t r = base + i*128 + qi;
        L += partL[r];
        O += partO[r*HD_ + d];
    }
    ctx[((size_t)(b*NQ_ + qi))*D_ + h*HD_ + d] = O / L;
}

// ---------------------------------------------------------------------------
// Workspace (bytes):
//   qp       @ 0           (1,638,400)
//   mpack    @ 1,638,400   (262,144)
//   wfull_bf @ 1,900,544   (6,291,456)
//   qn_bf    @ 8,192,000   (1,048,576)
//   ctx_cat  @ 9,240,576   (3,145,728)
//   wout_cat @ 12,386,304  (6,291,456)
//   P        @ 18,677,760  (16,777,216)
//   ctx      @ 35,454,976  (1,638,400)
//   partL    @ 37,093,376  (262,144)
//   partO    @ 37,355,520  (16,777,216)
//   kvn_bf   @ 54,132,736  (33,554,432)
//   kp       @ 87,687,168  (33,554,432)  bf16 [16384][1024]
//   vt       @ 121,241,600 (33,554,432)  bf16 [4096][4096]  -> ~154.8 MB
// ---------------------------------------------------------------------------
extern "C" void kernel_launch(void* const* d_in, const int* in_sizes, int n_in,
                              void* d_out, int out_size, void* d_ws, size_t ws_size,
                              hipStream_t stream)
{
    const float* q     = (const float*)d_in[0];
    const float* kv    = (const float*)d_in[1];
    const int*   mask  = (const int*)  d_in[2];
    const float* in_w  = (const float*)d_in[3];
    const float* in_b  = (const float*)d_in[4];
    const float* out_w = (const float*)d_in[5];
    const float* out_b = (const float*)d_in[6];
    const float* g_q   = (const float*)d_in[7];
    const float* b_q   = (const float*)d_in[8];
    const float* g_kv  = (const float*)d_in[9];
    const float* b_kv  = (const float*)d_in[10];
    float* out = (float*)d_out;

    char* ws = (char*)d_ws;
    float*          qp       = (float*)         (ws + 0);
    unsigned int*   mpackp   = (unsigned int*)  (ws + 1638400);
    unsigned short* wfull_bf = (unsigned short*)(ws + 1900544);
    unsigned short* qn_bf    = (unsigned short*)(ws + 8192000);
    unsigned short* ctx_cat  = (unsigned short*)(ws + 9240576);
    unsigned short* wout_cat = (unsigned short*)(ws + 12386304);
    float*          P        = (float*)         (ws + 18677760);
    float*          ctx      = (float*)         (ws + 35454976);
    float*          partL    = (float*)         (ws + 37093376);
    float*          partO    = (float*)         (ws + 37355520);
    unsigned short* kvn_bf   = (unsigned short*)(ws + 54132736);
    unsigned short* kp       = (unsigned short*)(ws + 87687168);
    unsigned short* vt       = (unsigned short*)(ws + 121241600);

    // --- prep ---
    mpack_kernel<<<dim3(128, B_), 256, 0, stream>>>(mask, mpackp);
    wconv_kernel<<<3*D_*D_/4/256, 256, 0, stream>>>(in_w, wfull_bf);
    ln_bf16_kernel<<<B_*HW_/4, 256, 0, stream>>>(kv, g_kv, b_kv, kvn_bf, B_*HW_);
    ln_bf16_kernel<<<MP_/4, 256, 0, stream>>>(q, g_q, b_q, qn_bf, B_*NQ_);

    // --- Q projection: split-K MFMA + reduce ---
    gemm_splitk_kernel<<<dim3(D_/64, MP_/64, 8), 256, 0, stream>>>(
        qn_bf, wfull_bf, P, D_, 128);
    reduce_kernel<<<B_*NQ_*D_/4/256, 256, 0, stream>>>(P, in_b, qp, 8);

    // --- K|V projection: bf16 MFMA; K -> kp, V -> vt (fused transpose) ---
    gemm_kv_kernel<<<dim3(16, B_*HW_/128), 256, 0, stream>>>(
        kvn_bf, wfull_bf + (size_t)D_*D_, in_b + D_, kp, vt);

    // --- MFMA flash attention + combine ---
    flash_kernel<<<dim3(4, H_, B_*NCH_), 256, 0, stream>>>(
        qp, kp, vt, mpackp, partO, partL);
    combine_kernel<<<dim3(NQ_, H_, B_), 64, 0, stream>>>(partO, partL, ctx);

    // --- Output projection: hi/lo split via split-K MFMA ---
    hilo_a_kernel<<<MP_, 256, 0, stream>>>(ctx, ctx_cat);
    hilo_w_kernel<<<D_, 256, 0, stream>>>(out_w, wout_cat);
    gemm_splitk_kernel<<<dim3(D_/64, MP_/64, 8), 256, 0, stream>>>(
        ctx_cat, wout_cat, P, 3*D_, 384);
    reduce_kernel<<<B_*NQ_*D_/4/256, 256, 0, stream>>>(P, out_b, out, 8);
}